// Round 5
// baseline (13296.252 us; speedup 1.0000x reference)
//
#include <hip/hip_runtime.h>
#include <hip/hip_bf16.h>
#include <math.h>

// Problem constants
#define NH    16
#define NOPE  128
#define ROPED 64
#define VD    128
#define QLR   1536
#define IH    8
#define ID    128
#define TOPK  8
#define EPSF  1e-5f
#define B_    2
#define S_    2048
#define H_    2048

using bf16 = __hip_bfloat16;

__device__ __forceinline__ float b2f(bf16 v) { return __bfloat162float(v); }
__device__ __forceinline__ bf16 f2b(float v) { return __float2bfloat16(v); }
__device__ __forceinline__ float us2f(unsigned int u) {
    union { unsigned int i; float f; } c; c.i = u << 16; return c.f;
}
__device__ __forceinline__ float toF(float v) { return v; }
__device__ __forceinline__ float toF(bf16 v) { return __bfloat162float(v); }
__device__ __forceinline__ void stoC(float* p, float v) { *p = v; }
__device__ __forceinline__ void stoC(bf16* p, float v) { *p = __float2bfloat16(v); }

// ---------------------------------------------------------------------------
// Generic tiled GEMM: C[M,N] = A[M,K] @ B[K,N]; fp32 accumulate.
// 64x64 tile, BK=16, 256 threads, 4x4 per thread. K % 16 == 0 assumed.
// (Proven bit-equivalent in comparison behavior to the naive GEMM, R3 vs R4.)
// ---------------------------------------------------------------------------
template <typename AT, typename BT, typename OT>
__global__ __launch_bounds__(256) void gemm_k(const AT* __restrict__ A,
                                              const BT* __restrict__ Bw,
                                              OT* __restrict__ C,
                                              int M, int N, int K) {
    __shared__ float As[64][17];
    __shared__ float Bs[16][64];
    const int t  = threadIdx.x;
    const int tx = t & 15, ty = t >> 4;
    const int row0 = blockIdx.y * 64;
    const int col0 = blockIdx.x * 64;
    const int ar = t >> 2;        // 0..63
    const int ac = (t & 3) * 4;   // 0,4,8,12
    const int br = t >> 4;        // 0..15
    const int bc = (t & 15) * 4;  // 0..60

    float acc[4][4] = {};

    for (int k0 = 0; k0 < K; k0 += 16) {
        {
            const int gr = row0 + ar;
            if (gr < M) {
                const AT* ap = A + (size_t)gr * K + k0 + ac;
                As[ar][ac + 0] = toF(ap[0]);
                As[ar][ac + 1] = toF(ap[1]);
                As[ar][ac + 2] = toF(ap[2]);
                As[ar][ac + 3] = toF(ap[3]);
            } else {
                As[ar][ac + 0] = 0.f; As[ar][ac + 1] = 0.f;
                As[ar][ac + 2] = 0.f; As[ar][ac + 3] = 0.f;
            }
        }
        {
            const int gk = k0 + br;
            const BT* bp = Bw + (size_t)gk * N + col0 + bc;
#pragma unroll
            for (int i = 0; i < 4; i++) {
                const int gc = col0 + bc + i;
                Bs[br][bc + i] = (gk < K && gc < N) ? toF(bp[i]) : 0.f;
            }
        }
        __syncthreads();
#pragma unroll
        for (int kk = 0; kk < 16; kk++) {
            float a[4], b[4];
#pragma unroll
            for (int i = 0; i < 4; i++) a[i] = As[ty * 4 + i][kk];
#pragma unroll
            for (int j = 0; j < 4; j++) b[j] = Bs[kk][tx * 4 + j];
#pragma unroll
            for (int i = 0; i < 4; i++)
#pragma unroll
                for (int j = 0; j < 4; j++) acc[i][j] += a[i] * b[j];
        }
        __syncthreads();
    }

#pragma unroll
    for (int i = 0; i < 4; i++) {
        const int gr = row0 + ty * 4 + i;
        if (gr >= M) continue;
#pragma unroll
        for (int j = 0; j < 4; j++) {
            const int gc = col0 + tx * 4 + j;
            if (gc >= N) continue;
            stoC(C + (size_t)gr * N + gc, acc[i][j]);
        }
    }
}

// ---------------------------------------------------------------------------
// Row layernorm (fp32, in-place), one block per row.
// ---------------------------------------------------------------------------
__global__ __launch_bounds__(256) void layernorm_k(float* __restrict__ X,
                                                   const float* __restrict__ w,
                                                   const float* __restrict__ b,
                                                   int L) {
    __shared__ float r1[256], r2[256];
    const int row = blockIdx.x;
    const int t = threadIdx.x;
    float* xp = X + (size_t)row * L;
    float s1 = 0.f, s2 = 0.f;
    for (int j = t; j < L; j += 256) { const float v = xp[j]; s1 += v; s2 += v * v; }
    r1[t] = s1; r2[t] = s2; __syncthreads();
    for (int off = 128; off > 0; off >>= 1) {
        if (t < off) { r1[t] += r1[t + off]; r2[t] += r2[t + off]; }
        __syncthreads();
    }
    const float mu   = r1[0] / (float)L;
    const float var  = r2[0] / (float)L - mu * mu;
    const float rinv = rsqrtf(var + EPSF);
    for (int j = t; j < L; j += 256)
        xp[j] = (xp[j] - mu) * rinv * w[j] + b[j];
}

// ---------------------------------------------------------------------------
// In-place RoPE on qp (bf16, layout (B,S,NH,192)); rotates slots [128:192].
// ---------------------------------------------------------------------------
__global__ __launch_bounds__(256) void q_rope_k(bf16* __restrict__ qp) {
    const int total = B_ * S_ * NH * 32;
    for (int p = blockIdx.x * 256 + threadIdx.x; p < total; p += gridDim.x * 256) {
        const int j = p & 31;
        const int row = p >> 5;          // (b*S + s)*NH + h
        const int sr = row >> 4;         // b*S + s
        const int s = sr & (S_ - 1);
        const size_t base = (size_t)row * 192 + 128 + 2 * j;
        const float xr = b2f(qp[base]);
        const float xi = b2f(qp[base + 1]);
        const float freq = powf(10000.f, -(float)(2 * j) / 64.f);
        const float ang = (float)s * freq;
        float sn, c; sincosf(ang, &sn, &c);
        qp[base]     = f2b(xr * c - xi * sn);
        qp[base + 1] = f2b(xr * sn + xi * c);
    }
}

// ---------------------------------------------------------------------------
// KV transform, IN PLACE on kvc (bf16, (B,S,NH,192)):
//   row = [k_pe(64) | kv_nope(128)] -> [k_nope(128) | rope(k_pe)(64)]
//   V (last 128 of LN(kv_nope) @ W_kv) -> Vb (B,NH,S,128) bf16.
// ---------------------------------------------------------------------------
__global__ __launch_bounds__(128) void kv_proc_k(bf16* __restrict__ kvc,
                                                 const float* __restrict__ knw,
                                                 const float* __restrict__ knb,
                                                 const float* __restrict__ Wkv,
                                                 bf16* __restrict__ Vb) {
    __shared__ float red[128];
    __shared__ float kvn[128];
    __shared__ float pe[64];
    const int idx = blockIdx.x;
    const int h = idx & (NH - 1);
    const int rest = idx >> 4;
    const int s = rest & (S_ - 1);
    const int b = rest >> 11;
    const size_t base = (size_t)idx * 192;
    const int t = threadIdx.x;

    const float v = b2f(kvc[base + 64 + t]);   // read slots 64..191 (kv_nope)
    if (t < 64) pe[t] = b2f(kvc[base + t]);    // read slots 0..63 (k_pe)
    red[t] = v; __syncthreads();
    for (int off = 64; off > 0; off >>= 1) { if (t < off) red[t] += red[t + off]; __syncthreads(); }
    const float mu = red[0] / 128.f;
    __syncthreads();
    const float d = v - mu;
    red[t] = d * d; __syncthreads();
    for (int off = 64; off > 0; off >>= 1) { if (t < off) red[t] += red[t + off]; __syncthreads(); }
    const float rinv = rsqrtf(red[0] / 128.f + EPSF);
    kvn[t] = d * rinv * knw[t] + knb[t];
    __syncthreads();   // all row reads done; kvn ready — writes are safe now

    const size_t vbase = ((size_t)(b * NH + h) * S_ + s) * 128;
#pragma unroll
    for (int rep = 0; rep < 2; rep++) {
        const int n = t + rep * 128;
        float acc = 0.f;
        for (int k = 0; k < 128; k++) acc += kvn[k] * Wkv[k * 256 + n];
        if (n < 128) kvc[base + n] = f2b(acc);       // K nope part
        else         Vb[vbase + n - 128] = f2b(acc); // V
    }
    if (t < 32) {
        const float xr = pe[2 * t];
        const float xi = pe[2 * t + 1];
        const float freq = powf(10000.f, -(float)(2 * t) / 64.f);
        const float ang = (float)s * freq;
        float sn, c; sincosf(ang, &sn, &c);
        kvc[base + 128 + 2 * t]     = f2b(xr * c - xi * sn);
        kvc[base + 128 + 2 * t + 1] = f2b(xr * sn + xi * c);
    }
}

// ---------------------------------------------------------------------------
// Sparse branch: per (b,ih): top-8 gate over S, mini-attention over 8 tokens,
// mean -> project through W_io[:, :VD].  16 blocks, 256 threads.
// ---------------------------------------------------------------------------
__global__ __launch_bounds__(256) void sparse_k(const float* __restrict__ gate,
                                                const float* __restrict__ ist,
                                                const float* __restrict__ Wsq,
                                                const float* __restrict__ Wsk,
                                                const float* __restrict__ Wsv,
                                                const float* __restrict__ Wio,
                                                float* __restrict__ io) {
    __shared__ float g[S_];
    __shared__ float sel[TOPK][ID];
    __shared__ float sq[TOPK][ID], sk[TOPK][ID], sv[TOPK][ID];
    __shared__ float sp[TOPK][TOPK];
    __shared__ float ms[ID];
    __shared__ float rv[256];
    __shared__ int ri[256];
    __shared__ int sidx[TOPK];
    const int bi = blockIdx.x;
    const int ih = bi % IH;
    const int b = bi / IH;
    const int t = threadIdx.x;

    for (int s = t; s < S_; s += 256) g[s] = gate[(size_t)(b * S_ + s) * IH + ih];
    __syncthreads();

    for (int r = 0; r < TOPK; r++) {
        float bv = -INFINITY; int bx = S_;
        for (int s = t; s < S_; s += 256) {
            const float v = g[s];
            if (v > bv) { bv = v; bx = s; }
        }
        rv[t] = bv; ri[t] = bx; __syncthreads();
        for (int off = 128; off > 0; off >>= 1) {
            if (t < off) {
                const float v2 = rv[t + off]; const int i2 = ri[t + off];
                if (v2 > rv[t] || (v2 == rv[t] && i2 < ri[t])) { rv[t] = v2; ri[t] = i2; }
            }
            __syncthreads();
        }
        if (t == 0) { sidx[r] = ri[0]; g[ri[0]] = -INFINITY; }
        __syncthreads();
    }

    for (int i = t; i < TOPK * ID; i += 256) {
        const int r = i >> 7, d = i & 127;
        sel[r][d] = ist[((size_t)(b * S_ + sidx[r]) * IH + ih) * ID + d];
    }
    __syncthreads();

    for (int i = t; i < TOPK * ID; i += 256) {
        const int r = i >> 7, n = i & 127;
        float aq = 0.f, ak = 0.f, av = 0.f;
        for (int k = 0; k < 128; k++) {
            const float s = sel[r][k];
            aq += s * Wsq[k * ID + n];
            ak += s * Wsk[k * ID + n];
            av += s * Wsv[k * ID + n];
        }
        sq[r][n] = aq; sk[r][n] = ak; sv[r][n] = av;
    }
    __syncthreads();

    if (t < TOPK * TOPK) {
        const int r = t >> 3, c = t & 7;
        float a = 0.f;
        for (int k = 0; k < 128; k++) a += sq[r][k] * sk[c][k];
        sp[r][c] = a * 0.08838834764831845f;  // 1/sqrt(128)
    }
    __syncthreads();

    if (t < TOPK) {
        float m = -INFINITY;
        for (int c = 0; c < 8; c++) m = fmaxf(m, sp[t][c]);
        float e[8]; float sum = 0.f;
        for (int c = 0; c < 8; c++) { e[c] = expf(sp[t][c] - m); sum += e[c]; }
        for (int c = 0; c < 8; c++) sp[t][c] = e[c] / sum;
    }
    __syncthreads();

    if (t < ID) {
        float acc = 0.f;
        for (int r = 0; r < 8; r++) {
            float so = 0.f;
            for (int c = 0; c < 8; c++) so += sp[r][c] * sv[c][t];
            acc += so;
        }
        ms[t] = acc * 0.125f;  // mean over TOPK
    }
    __syncthreads();

    if (t < ID) {
        float acc = 0.f;
        for (int k = 0; k < 128; k++) acc += ms[k] * Wio[(size_t)k * H_ + t];
        io[((size_t)b * IH + ih) * ID + t] = acc;
    }
}

// ---------------------------------------------------------------------------
// Causal attention, one block (256 thr) per (qi, h, b).
// Q from qp (B,S,NH,192) bf16; K in-place in kvc (B,S,NH,192) bf16;
// V (B,NH,S,128) bf16. Scores fp32 in LDS; adds sparse io; writes fp32
// attn as (B,S,NH*VD) ready for the final GEMM.
// ---------------------------------------------------------------------------
__global__ __launch_bounds__(256) void attn_k(const bf16* __restrict__ Qp,
                                              const bf16* __restrict__ Kc,
                                              const bf16* __restrict__ Vb,
                                              const float* __restrict__ io,
                                              float* __restrict__ O) {
    __shared__ float q_s[192];
    __shared__ float sc[S_];
    __shared__ float red[256];
    const int qi = blockIdx.x, h = blockIdx.y, b = blockIdx.z;
    const int t = threadIdx.x;

    if (t < 192) q_s[t] = b2f(Qp[((size_t)(b * S_ + qi) * NH + h) * 192 + t]);
    __syncthreads();

    const int nk = qi + 1;
    const float scale = 0.07216878364870322f;  // 1/sqrt(192)

    float lmax = -INFINITY;
    for (int ki = t; ki < nk; ki += 256) {
        const uint4* kp = (const uint4*)(Kc + ((size_t)(b * S_ + ki) * NH + h) * 192);
        float acc = 0.f;
#pragma unroll
        for (int w = 0; w < 24; w++) {
            const uint4 kk = kp[w];
            const int e = w * 8;
            acc += q_s[e + 0] * us2f(kk.x & 0xffffu) + q_s[e + 1] * us2f(kk.x >> 16);
            acc += q_s[e + 2] * us2f(kk.y & 0xffffu) + q_s[e + 3] * us2f(kk.y >> 16);
            acc += q_s[e + 4] * us2f(kk.z & 0xffffu) + q_s[e + 5] * us2f(kk.z >> 16);
            acc += q_s[e + 6] * us2f(kk.w & 0xffffu) + q_s[e + 7] * us2f(kk.w >> 16);
        }
        acc *= scale;
        sc[ki] = acc;
        lmax = fmaxf(lmax, acc);
    }
    red[t] = lmax; __syncthreads();
    for (int off = 128; off > 0; off >>= 1) {
        if (t < off) red[t] = fmaxf(red[t], red[t + off]);
        __syncthreads();
    }
    const float m = red[0];
    __syncthreads();

    float lsum = 0.f;
    for (int ki = t; ki < nk; ki += 256) {
        const float p = expf(sc[ki] - m);
        sc[ki] = p;
        lsum += p;
    }
    red[t] = lsum; __syncthreads();
    for (int off = 128; off > 0; off >>= 1) {
        if (t < off) red[t] += red[t + off];
        __syncthreads();
    }
    const float l = red[0];
    __syncthreads();

    // P @ V : thread t -> dim d = t&127, halves split keys even/odd
    const int half = t >> 7, d = t & 127;
    const size_t vhead = ((size_t)(b * NH + h) * S_) * 128;
    float acc = 0.f;
    for (int ki = half; ki < nk; ki += 2)
        acc += sc[ki] * b2f(Vb[vhead + (size_t)ki * 128 + d]);
    if (half == 1) red[d] = acc;
    __syncthreads();
    if (half == 0) {
        const float tot = acc + red[d];
        const float o = tot / l;
        const float iov = io[((size_t)b * IH + (h >> 1)) * ID + d];
        O[(((size_t)b * S_ + qi) * NH + h) * VD + d] = o + iov;
    }
}

// ---------------------------------------------------------------------------
extern "C" void kernel_launch(void* const* d_in, const int* in_sizes, int n_in,
                              void* d_out, int out_size, void* d_ws, size_t ws_size,
                              hipStream_t stream) {
    // Inputs fp32 (reference setup_inputs). OUTPUT fp32 (reference returns
    // fp32; harness compares in bf16 domain but stores fp32 — "else float*").
    const float* x      = (const float*)d_in[0];
    const float* W_cq   = (const float*)d_in[1];
    const float* qn_w   = (const float*)d_in[2];
    const float* qn_b   = (const float*)d_in[3];
    const float* W_q    = (const float*)d_in[4];
    const float* W_ckv  = (const float*)d_in[5];
    const float* kvn_w  = (const float*)d_in[6];
    const float* kvn_b  = (const float*)d_in[7];
    const float* W_kv   = (const float*)d_in[8];
    const float* W_o    = (const float*)d_in[9];
    const float* W_ip   = (const float*)d_in[10];
    const float* W_ig   = (const float*)d_in[11];
    const float* W_sq   = (const float*)d_in[12];
    const float* W_sk   = (const float*)d_in[13];
    const float* W_sv   = (const float*)d_in[14];
    const float* W_io   = (const float*)d_in[15];
    float* out = (float*)d_out;   // <-- fp32, per reference output dtype

    const int M = B_ * S_;  // 4096 token rows

    // Workspace layout (~100.8 MB, proven non-faulting in R2-R4):
    char* wsb = (char*)d_ws;
    float* rbig = (float*)wsb;                    // 8,388,608 floats
    bf16*  qp   = (bf16*)(wsb + 33554432);        // 12,582,912 bf16
    bf16*  kvc  = (bf16*)(wsb + 58720256);        // 12,582,912 bf16
    bf16*  Vb   = (bf16*)(wsb + 83886080);        //  8,388,608 bf16
    float* gate = (float*)(wsb + 100663296);      // 32,768 floats
    float* iob  = (float*)(wsb + 100794368);      //  2,048 floats
    float* cq   = rbig;
    float* ist  = rbig;
    float* attn = rbig;

    dim3 blk(256);

    // 1. cq = x @ W_cq  (fp32)
    gemm_k<float, float, float><<<dim3(QLR / 64, M / 64), blk, 0, stream>>>(x, W_cq, cq, M, QLR, H_);
    // 2. layernorm(cq) in place
    layernorm_k<<<dim3(M), blk, 0, stream>>>(cq, qn_w, qn_b, QLR);
    // 3. qp = qc @ W_q  (bf16)
    gemm_k<float, float, bf16><<<dim3(3072 / 64, M / 64), blk, 0, stream>>>(cq, W_q, qp, M, 3072, QLR);
    // 4. kvc = x @ W_ckv  (bf16)
    gemm_k<float, float, bf16><<<dim3(3072 / 64, M / 64), blk, 0, stream>>>(x, W_ckv, kvc, M, 3072, H_);
    // 5. ist = x @ W_ip  (fp32, overwrites cq region — cq dead after step 3)
    gemm_k<float, float, float><<<dim3(1024 / 64, M / 64), blk, 0, stream>>>(x, W_ip, ist, M, IH * ID, H_);
    // 6. gate = x @ W_ig  (fp32)
    gemm_k<float, float, float><<<dim3(1, M / 64), blk, 0, stream>>>(x, W_ig, gate, M, IH, H_);
    // 7. RoPE on qp in place
    q_rope_k<<<dim3(2048), blk, 0, stream>>>(qp);
    // 8. KV: LN + W_kv projection (K in place in kvc) + RoPE; V -> Vb
    kv_proc_k<<<dim3(B_ * S_ * NH), dim3(128), 0, stream>>>(kvc, kvn_w, kvn_b, W_kv, Vb);
    // 9. sparse branch -> iob (B,IH,VD)
    sparse_k<<<dim3(B_ * IH), blk, 0, stream>>>(gate, ist, W_sq, W_sk, W_sv, W_io, iob);
    // 10. attention (+io) -> attn (B,S,NH*VD) fp32 (overwrites ist region — dead after 9)
    attn_k<<<dim3(S_, NH, B_), blk, 0, stream>>>(qp, kvc, Vb, iob, attn);
    // 11. out = attn @ W_o  -> fp32 d_out
    gemm_k<float, float, float><<<dim3(H_ / 64, M / 64), blk, 0, stream>>>(attn, W_o, out, M, H_, H_);
}

// Round 6
// 3504.563 us; speedup vs baseline: 3.7940x; 3.7940x over previous
//
#include <hip/hip_runtime.h>
#include <hip/hip_bf16.h>
#include <math.h>

// Problem constants
#define NH    16
#define NOPE  128
#define ROPED 64
#define VD    128
#define QLR   1536
#define IH    8
#define ID    128
#define TOPK  8
#define EPSF  1e-5f
#define B_    2
#define S_    2048
#define H_    2048

using bf16 = __hip_bfloat16;
typedef __attribute__((ext_vector_type(8))) short short8;
typedef __attribute__((ext_vector_type(4))) float f32x4;

__device__ __forceinline__ float b2f(bf16 v) { return __bfloat162float(v); }
__device__ __forceinline__ bf16 f2b(float v) { return __float2bfloat16(v); }
__device__ __forceinline__ float toF(float v) { return v; }
__device__ __forceinline__ float toF(bf16 v) { return __bfloat162float(v); }
__device__ __forceinline__ void stoC(float* p, float v) { *p = v; }
__device__ __forceinline__ void stoC(bf16* p, float v) { *p = __float2bfloat16(v); }

// ---------------------------------------------------------------------------
// Generic tiled GEMM (unchanged from passing R5): C = A @ B, fp32 accumulate.
// ---------------------------------------------------------------------------
template <typename AT, typename BT, typename OT>
__global__ __launch_bounds__(256) void gemm_k(const AT* __restrict__ A,
                                              const BT* __restrict__ Bw,
                                              OT* __restrict__ C,
                                              int M, int N, int K) {
    __shared__ float As[64][17];
    __shared__ float Bs[16][64];
    const int t  = threadIdx.x;
    const int tx = t & 15, ty = t >> 4;
    const int row0 = blockIdx.y * 64;
    const int col0 = blockIdx.x * 64;
    const int ar = t >> 2;
    const int ac = (t & 3) * 4;
    const int br = t >> 4;
    const int bc = (t & 15) * 4;

    float acc[4][4] = {};

    for (int k0 = 0; k0 < K; k0 += 16) {
        {
            const int gr = row0 + ar;
            if (gr < M) {
                const AT* ap = A + (size_t)gr * K + k0 + ac;
                As[ar][ac + 0] = toF(ap[0]);
                As[ar][ac + 1] = toF(ap[1]);
                As[ar][ac + 2] = toF(ap[2]);
                As[ar][ac + 3] = toF(ap[3]);
            } else {
                As[ar][ac + 0] = 0.f; As[ar][ac + 1] = 0.f;
                As[ar][ac + 2] = 0.f; As[ar][ac + 3] = 0.f;
            }
        }
        {
            const int gk = k0 + br;
            const BT* bp = Bw + (size_t)gk * N + col0 + bc;
#pragma unroll
            for (int i = 0; i < 4; i++) {
                const int gc = col0 + bc + i;
                Bs[br][bc + i] = (gk < K && gc < N) ? toF(bp[i]) : 0.f;
            }
        }
        __syncthreads();
#pragma unroll
        for (int kk = 0; kk < 16; kk++) {
            float a[4], b[4];
#pragma unroll
            for (int i = 0; i < 4; i++) a[i] = As[ty * 4 + i][kk];
#pragma unroll
            for (int j = 0; j < 4; j++) b[j] = Bs[kk][tx * 4 + j];
#pragma unroll
            for (int i = 0; i < 4; i++)
#pragma unroll
                for (int j = 0; j < 4; j++) acc[i][j] += a[i] * b[j];
        }
        __syncthreads();
    }

#pragma unroll
    for (int i = 0; i < 4; i++) {
        const int gr = row0 + ty * 4 + i;
        if (gr >= M) continue;
#pragma unroll
        for (int j = 0; j < 4; j++) {
            const int gc = col0 + tx * 4 + j;
            if (gc >= N) continue;
            stoC(C + (size_t)gr * N + gc, acc[i][j]);
        }
    }
}

// ---------------------------------------------------------------------------
// Row layernorm (unchanged).
// ---------------------------------------------------------------------------
__global__ __launch_bounds__(256) void layernorm_k(float* __restrict__ X,
                                                   const float* __restrict__ w,
                                                   const float* __restrict__ b,
                                                   int L) {
    __shared__ float r1[256], r2[256];
    const int row = blockIdx.x;
    const int t = threadIdx.x;
    float* xp = X + (size_t)row * L;
    float s1 = 0.f, s2 = 0.f;
    for (int j = t; j < L; j += 256) { const float v = xp[j]; s1 += v; s2 += v * v; }
    r1[t] = s1; r2[t] = s2; __syncthreads();
    for (int off = 128; off > 0; off >>= 1) {
        if (t < off) { r1[t] += r1[t + off]; r2[t] += r2[t + off]; }
        __syncthreads();
    }
    const float mu   = r1[0] / (float)L;
    const float var  = r2[0] / (float)L - mu * mu;
    const float rinv = rsqrtf(var + EPSF);
    for (int j = t; j < L; j += 256)
        xp[j] = (xp[j] - mu) * rinv * w[j] + b[j];
}

// ---------------------------------------------------------------------------
// In-place RoPE on qp (unchanged).
// ---------------------------------------------------------------------------
__global__ __launch_bounds__(256) void q_rope_k(bf16* __restrict__ qp) {
    const int total = B_ * S_ * NH * 32;
    for (int p = blockIdx.x * 256 + threadIdx.x; p < total; p += gridDim.x * 256) {
        const int j = p & 31;
        const int row = p >> 5;
        const int sr = row >> 4;
        const int s = sr & (S_ - 1);
        const size_t base = (size_t)row * 192 + 128 + 2 * j;
        const float xr = b2f(qp[base]);
        const float xi = b2f(qp[base + 1]);
        const float freq = powf(10000.f, -(float)(2 * j) / 64.f);
        const float ang = (float)s * freq;
        float sn, c; sincosf(ang, &sn, &c);
        qp[base]     = f2b(xr * c - xi * sn);
        qp[base + 1] = f2b(xr * sn + xi * c);
    }
}

// ---------------------------------------------------------------------------
// KV transform (unchanged).
// ---------------------------------------------------------------------------
__global__ __launch_bounds__(128) void kv_proc_k(bf16* __restrict__ kvc,
                                                 const float* __restrict__ knw,
                                                 const float* __restrict__ knb,
                                                 const float* __restrict__ Wkv,
                                                 bf16* __restrict__ Vb) {
    __shared__ float red[128];
    __shared__ float kvn[128];
    __shared__ float pe[64];
    const int idx = blockIdx.x;
    const int h = idx & (NH - 1);
    const int rest = idx >> 4;
    const int s = rest & (S_ - 1);
    const int b = rest >> 11;
    const size_t base = (size_t)idx * 192;
    const int t = threadIdx.x;

    const float v = b2f(kvc[base + 64 + t]);
    if (t < 64) pe[t] = b2f(kvc[base + t]);
    red[t] = v; __syncthreads();
    for (int off = 64; off > 0; off >>= 1) { if (t < off) red[t] += red[t + off]; __syncthreads(); }
    const float mu = red[0] / 128.f;
    __syncthreads();
    const float d = v - mu;
    red[t] = d * d; __syncthreads();
    for (int off = 64; off > 0; off >>= 1) { if (t < off) red[t] += red[t + off]; __syncthreads(); }
    const float rinv = rsqrtf(red[0] / 128.f + EPSF);
    kvn[t] = d * rinv * knw[t] + knb[t];
    __syncthreads();

    const size_t vbase = ((size_t)(b * NH + h) * S_ + s) * 128;
#pragma unroll
    for (int rep = 0; rep < 2; rep++) {
        const int n = t + rep * 128;
        float acc = 0.f;
        for (int k = 0; k < 128; k++) acc += kvn[k] * Wkv[k * 256 + n];
        if (n < 128) kvc[base + n] = f2b(acc);
        else         Vb[vbase + n - 128] = f2b(acc);
    }
    if (t < 32) {
        const float xr = pe[2 * t];
        const float xi = pe[2 * t + 1];
        const float freq = powf(10000.f, -(float)(2 * t) / 64.f);
        const float ang = (float)s * freq;
        float sn, c; sincosf(ang, &sn, &c);
        kvc[base + 128 + 2 * t]     = f2b(xr * c - xi * sn);
        kvc[base + 128 + 2 * t + 1] = f2b(xr * sn + xi * c);
    }
}

// ---------------------------------------------------------------------------
// Sparse branch (unchanged).
// ---------------------------------------------------------------------------
__global__ __launch_bounds__(256) void sparse_k(const float* __restrict__ gate,
                                                const float* __restrict__ ist,
                                                const float* __restrict__ Wsq,
                                                const float* __restrict__ Wsk,
                                                const float* __restrict__ Wsv,
                                                const float* __restrict__ Wio,
                                                float* __restrict__ io) {
    __shared__ float g[S_];
    __shared__ float sel[TOPK][ID];
    __shared__ float sq[TOPK][ID], sk[TOPK][ID], sv[TOPK][ID];
    __shared__ float sp[TOPK][TOPK];
    __shared__ float ms[ID];
    __shared__ float rv[256];
    __shared__ int ri[256];
    __shared__ int sidx[TOPK];
    const int bi = blockIdx.x;
    const int ih = bi % IH;
    const int b = bi / IH;
    const int t = threadIdx.x;

    for (int s = t; s < S_; s += 256) g[s] = gate[(size_t)(b * S_ + s) * IH + ih];
    __syncthreads();

    for (int r = 0; r < TOPK; r++) {
        float bv = -INFINITY; int bx = S_;
        for (int s = t; s < S_; s += 256) {
            const float v = g[s];
            if (v > bv) { bv = v; bx = s; }
        }
        rv[t] = bv; ri[t] = bx; __syncthreads();
        for (int off = 128; off > 0; off >>= 1) {
            if (t < off) {
                const float v2 = rv[t + off]; const int i2 = ri[t + off];
                if (v2 > rv[t] || (v2 == rv[t] && i2 < ri[t])) { rv[t] = v2; ri[t] = i2; }
            }
            __syncthreads();
        }
        if (t == 0) { sidx[r] = ri[0]; g[ri[0]] = -INFINITY; }
        __syncthreads();
    }

    for (int i = t; i < TOPK * ID; i += 256) {
        const int r = i >> 7, d = i & 127;
        sel[r][d] = ist[((size_t)(b * S_ + sidx[r]) * IH + ih) * ID + d];
    }
    __syncthreads();

    for (int i = t; i < TOPK * ID; i += 256) {
        const int r = i >> 7, n = i & 127;
        float aq = 0.f, ak = 0.f, av = 0.f;
        for (int k = 0; k < 128; k++) {
            const float s = sel[r][k];
            aq += s * Wsq[k * ID + n];
            ak += s * Wsk[k * ID + n];
            av += s * Wsv[k * ID + n];
        }
        sq[r][n] = aq; sk[r][n] = ak; sv[r][n] = av;
    }
    __syncthreads();

    if (t < TOPK * TOPK) {
        const int r = t >> 3, c = t & 7;
        float a = 0.f;
        for (int k = 0; k < 128; k++) a += sq[r][k] * sk[c][k];
        sp[r][c] = a * 0.08838834764831845f;
    }
    __syncthreads();

    if (t < TOPK) {
        float m = -INFINITY;
        for (int c = 0; c < 8; c++) m = fmaxf(m, sp[t][c]);
        float e[8]; float sum = 0.f;
        for (int c = 0; c < 8; c++) { e[c] = expf(sp[t][c] - m); sum += e[c]; }
        for (int c = 0; c < 8; c++) sp[t][c] = e[c] / sum;
    }
    __syncthreads();

    if (t < ID) {
        float acc = 0.f;
        for (int r = 0; r < 8; r++) {
            float so = 0.f;
            for (int c = 0; c < 8; c++) so += sp[r][c] * sv[c][t];
            acc += so;
        }
        ms[t] = acc * 0.125f;
    }
    __syncthreads();

    if (t < ID) {
        float acc = 0.f;
        for (int k = 0; k < 128; k++) acc += ms[k] * Wio[(size_t)k * H_ + t];
        io[((size_t)b * IH + ih) * ID + t] = acc;
    }
}

// ---------------------------------------------------------------------------
// MFMA flash attention. Block = 256 thr (4 waves), covers 64 queries of one
// (b,h). K-tiles of 32 staged in LDS; online softmax; P via bf16 LDS
// roundtrip (C-layout -> A-layout, m120 pattern); V transposed in LDS for
// the PV B-frag. Verified layouts: C/D col=lane&15,row=quad*4+reg (m89);
// A[m=lane&15][k=quad*8+j] (m120). Scores = Q·K^T is the gemm_bt shape, so
// K rows read naturally as B-frags.
// ---------------------------------------------------------------------------
__global__ __launch_bounds__(256) void attn_mfma_k(const bf16* __restrict__ Qp,
                                                   const bf16* __restrict__ Kc,
                                                   const bf16* __restrict__ Vb,
                                                   const float* __restrict__ io,
                                                   float* __restrict__ O) {
    __shared__ unsigned short Kt[32 * 200];   // K-tile, row stride 200 (pad)
    __shared__ unsigned short Vt[128 * 40];   // V-tile transposed, stride 40
    __shared__ unsigned short Ps[4 * 16 * 40];// per-wave P patch, stride 40
    __shared__ float io_s[128];

    const int qt = blockIdx.x, h = blockIdx.y, b = blockIdx.z;
    const int q0 = qt * 64;
    const int t = threadIdx.x;
    const int lane = t & 63;
    const int wq = t >> 6;            // wave id -> 16-query subtile
    const int col = lane & 15;        // n-index (key within tile / dv)
    const int quad = lane >> 4;       // 0..3

    if (t < 128) io_s[t] = io[((size_t)b * IH + (h >> 1)) * ID + t];

    // Q fragments in registers for the whole kernel.
    // m = q0 + wq*16 + col ; d = kc*32 + quad*8 + j
    short8 qfrag[6];
    {
        const int q = q0 + wq * 16 + col;
        const short8* qrow = (const short8*)(Qp + ((size_t)(b * S_ + q) * NH + h) * 192);
#pragma unroll
        for (int kc = 0; kc < 6; kc++) qfrag[kc] = qrow[kc * 4 + quad];
    }

    float m_r[4], l_r[4];
#pragma unroll
    for (int r = 0; r < 4; r++) { m_r[r] = -1e30f; l_r[r] = 0.f; }
    f32x4 accO[8];
#pragma unroll
    for (int nt = 0; nt < 8; nt++) accO[nt] = (f32x4){0.f, 0.f, 0.f, 0.f};

    const int nkt = qt * 2 + 2;       // K-tiles needed (keys 0 .. q0+63)
    const float scale = 0.07216878364870322f;  // 1/sqrt(192)

    for (int kt = 0; kt < nkt; kt++) {
        const int kt0 = kt * 32;
        __syncthreads();   // protect Kt/Vt from previous iteration's readers
        // Stage K-tile: 32 rows x 192 bf16. Thread t: row t/8, cols (t%8)*24..+24.
        {
            const int kr = t >> 3;
            const int c0 = (t & 7) * 24;
            const short8* src = (const short8*)(Kc + ((size_t)(b * S_ + kt0 + kr) * NH + h) * 192 + c0);
            short8* dst = (short8*)&Kt[kr * 200 + c0];
            dst[0] = src[0]; dst[1] = src[1]; dst[2] = src[2];
        }
        // Stage V-tile transposed: Vt[dv][ki]. Thread t: ki=t>>3, dv=(t&7)+8j.
        {
            const int ki = t >> 3;
            const bf16* vrow = Vb + ((size_t)(b * NH + h) * S_ + kt0 + ki) * 128;
#pragma unroll
            for (int j = 0; j < 16; j++) {
                const int dv = (t & 7) + 8 * j;
                Vt[dv * 40 + ki] = *(const unsigned short*)(vrow + dv);
            }
        }
        __syncthreads();

        // Scores: two 16-key n-tiles, K=192 in 6 mfma steps each.
        f32x4 s[2];
#pragma unroll
        for (int nt = 0; nt < 2; nt++) {
            f32x4 acc = (f32x4){0.f, 0.f, 0.f, 0.f};
#pragma unroll
            for (int kc = 0; kc < 6; kc++) {
                const short8 kf = *(const short8*)&Kt[(nt * 16 + col) * 200 + kc * 32 + quad * 8];
                acc = __builtin_amdgcn_mfma_f32_16x16x32_bf16(qfrag[kc], kf, acc, 0, 0, 0);
            }
            s[nt] = acc;
        }
        // Scale + causal mask (row = query = quad*4+r, col = key).
#pragma unroll
        for (int nt = 0; nt < 2; nt++)
#pragma unroll
            for (int r = 0; r < 4; r++) {
                const int kg = kt0 + nt * 16 + col;
                const int qg = q0 + wq * 16 + quad * 4 + r;
                const float v = s[nt][r] * scale;
                s[nt][r] = (kg > qg) ? -1e30f : v;
            }
        // Online softmax per query row (16 lanes per row; xor-shuffle reduce).
        float alpha[4];
#pragma unroll
        for (int r = 0; r < 4; r++) {
            float mt = fmaxf(s[0][r], s[1][r]);
            mt = fmaxf(mt, __shfl_xor(mt, 1));
            mt = fmaxf(mt, __shfl_xor(mt, 2));
            mt = fmaxf(mt, __shfl_xor(mt, 4));
            mt = fmaxf(mt, __shfl_xor(mt, 8));
            const float mn = fmaxf(m_r[r], mt);
            alpha[r] = __expf(m_r[r] - mn);
            m_r[r] = mn;
            const float p0 = __expf(s[0][r] - mn);
            const float p1 = __expf(s[1][r] - mn);
            s[0][r] = p0; s[1][r] = p1;
            float rs = p0 + p1;
            rs += __shfl_xor(rs, 1);
            rs += __shfl_xor(rs, 2);
            rs += __shfl_xor(rs, 4);
            rs += __shfl_xor(rs, 8);
            l_r[r] = l_r[r] * alpha[r] + rs;
        }
        // P (C-layout) -> bf16 LDS -> reread in A-layout (per-wave region).
        {
            unsigned short* pw = &Ps[wq * 640];
#pragma unroll
            for (int nt = 0; nt < 2; nt++)
#pragma unroll
                for (int r = 0; r < 4; r++) {
                    bf16 hv = f2b(s[nt][r]);
                    pw[(quad * 4 + r) * 40 + nt * 16 + col] = *(unsigned short*)&hv;
                }
        }
        const short8 pfrag = *(const short8*)&Ps[wq * 640 + col * 40 + quad * 8];
        // Rescale O accumulators by alpha, then accumulate P·V.
#pragma unroll
        for (int nt = 0; nt < 8; nt++)
#pragma unroll
            for (int r = 0; r < 4; r++) accO[nt][r] *= alpha[r];
#pragma unroll
        for (int nt = 0; nt < 8; nt++) {
            const short8 vf = *(const short8*)&Vt[(nt * 16 + col) * 40 + quad * 8];
            accO[nt] = __builtin_amdgcn_mfma_f32_16x16x32_bf16(pfrag, vf, accO[nt], 0, 0, 0);
        }
    }

    // Epilogue: O = accO/l + io; write (B,S,NH*VD).
    float rinv[4];
#pragma unroll
    for (int r = 0; r < 4; r++) rinv[r] = 1.f / l_r[r];
#pragma unroll
    for (int nt = 0; nt < 8; nt++) {
        const int dv = nt * 16 + col;
        const float iov = io_s[dv];
#pragma unroll
        for (int r = 0; r < 4; r++) {
            const int q = q0 + wq * 16 + quad * 4 + r;
            O[((size_t)(b * S_ + q) * NH + h) * VD + dv] = accO[nt][r] * rinv[r] + iov;
        }
    }
}

// ---------------------------------------------------------------------------
extern "C" void kernel_launch(void* const* d_in, const int* in_sizes, int n_in,
                              void* d_out, int out_size, void* d_ws, size_t ws_size,
                              hipStream_t stream) {
    const float* x      = (const float*)d_in[0];
    const float* W_cq   = (const float*)d_in[1];
    const float* qn_w   = (const float*)d_in[2];
    const float* qn_b   = (const float*)d_in[3];
    const float* W_q    = (const float*)d_in[4];
    const float* W_ckv  = (const float*)d_in[5];
    const float* kvn_w  = (const float*)d_in[6];
    const float* kvn_b  = (const float*)d_in[7];
    const float* W_kv   = (const float*)d_in[8];
    const float* W_o    = (const float*)d_in[9];
    const float* W_ip   = (const float*)d_in[10];
    const float* W_ig   = (const float*)d_in[11];
    const float* W_sq   = (const float*)d_in[12];
    const float* W_sk   = (const float*)d_in[13];
    const float* W_sv   = (const float*)d_in[14];
    const float* W_io   = (const float*)d_in[15];
    float* out = (float*)d_out;

    const int M = B_ * S_;

    // Workspace layout (~100.8 MB, proven):
    char* wsb = (char*)d_ws;
    float* rbig = (float*)wsb;
    bf16*  qp   = (bf16*)(wsb + 33554432);
    bf16*  kvc  = (bf16*)(wsb + 58720256);
    bf16*  Vb   = (bf16*)(wsb + 83886080);
    float* gate = (float*)(wsb + 100663296);
    float* iob  = (float*)(wsb + 100794368);
    float* cq   = rbig;
    float* ist  = rbig;
    float* attn = rbig;

    dim3 blk(256);

    gemm_k<float, float, float><<<dim3(QLR / 64, M / 64), blk, 0, stream>>>(x, W_cq, cq, M, QLR, H_);
    layernorm_k<<<dim3(M), blk, 0, stream>>>(cq, qn_w, qn_b, QLR);
    gemm_k<float, float, bf16><<<dim3(3072 / 64, M / 64), blk, 0, stream>>>(cq, W_q, qp, M, 3072, QLR);
    gemm_k<float, float, bf16><<<dim3(3072 / 64, M / 64), blk, 0, stream>>>(x, W_ckv, kvc, M, 3072, H_);
    gemm_k<float, float, float><<<dim3(1024 / 64, M / 64), blk, 0, stream>>>(x, W_ip, ist, M, IH * ID, H_);
    gemm_k<float, float, float><<<dim3(1, M / 64), blk, 0, stream>>>(x, W_ig, gate, M, IH, H_);
    q_rope_k<<<dim3(2048), blk, 0, stream>>>(qp);
    kv_proc_k<<<dim3(B_ * S_ * NH), dim3(128), 0, stream>>>(kvc, kvn_w, kvn_b, W_kv, Vb);
    sparse_k<<<dim3(B_ * IH), blk, 0, stream>>>(gate, ist, W_sq, W_sk, W_sv, W_io, iob);
    // MFMA flash attention: 32 q-tiles x 16 heads x 2 batch
    attn_mfma_k<<<dim3(S_ / 64, NH, B_), blk, 0, stream>>>(qp, kvc, Vb, iob, attn);
    gemm_k<float, float, float><<<dim3(H_ / 64, M / 64), blk, 0, stream>>>(attn, W_o, out, M, H_, H_);
}